// Round 8
// baseline (43771.518 us; speedup 1.0000x reference)
//
#include <hip/hip_runtime.h>
#include <math.h>

// ---------------------------------------------------------------------------
// GOTSim: GCN features -> reduced 384x384 LAP (exact JV: col-reduction +
// fused greedy/u-init + augmenting row reduction + free-column dual
// reduction + shortest augmenting path with batched EXACT tie-popping).
// Tightness invariant u[i] == C[i][xr[i]] - v[xr[i]] held BITWISE so the
// relax d = min_val + ((c - v) - u) reproduces min_val exactly on the
// zero-slack plateau -> whole fronts pop per iteration.
// LAP_768(block) = Sum(D)+Sum(I) + LAP_384(min(0, M_ij - D_i - I_j)).
// ---------------------------------------------------------------------------

namespace {
constexpr int kN   = 384;   // nodes per graph == reduced LAP dimension
constexpr int kNN  = 768;   // original LAP dimension (for normalization)
constexpr int kE   = 3072;  // edges per graph
constexpr float kInf = 1e30f;
}

// ---- wave64 reductions via DPP (row_shr 1,2,4,8 + row_bcast 15,31) --------
__device__ __forceinline__ float wave_min_bcast(float xv) {
    float v = xv;
    #define MSTAGE(ctrl) { int t = __builtin_amdgcn_update_dpp(__float_as_int(v), __float_as_int(v), ctrl, 0xF, 0xF, false); v = fminf(v, __int_as_float(t)); }
    MSTAGE(0x111); MSTAGE(0x112); MSTAGE(0x114); MSTAGE(0x118); MSTAGE(0x142); MSTAGE(0x143);
    #undef MSTAGE
    return __int_as_float(__builtin_amdgcn_readlane(__float_as_int(v), 63));
}

// (min, second-min): disabled lanes contribute identity (+inf) via old=INF.
__device__ __forceinline__ void wave_min2_bcast(float m1, float m2, float& w1, float& w2) {
    const int INFB = __float_as_int(kInf);
    #define M2STAGE(ctrl) { \
        int t1 = __builtin_amdgcn_update_dpp(INFB, __float_as_int(m1), ctrl, 0xF, 0xF, false); \
        int t2 = __builtin_amdgcn_update_dpp(INFB, __float_as_int(m2), ctrl, 0xF, 0xF, false); \
        float o1 = __int_as_float(t1); float o2 = __int_as_float(t2); \
        float n2 = fminf(fmaxf(m1, o1), fminf(m2, o2)); \
        m1 = fminf(m1, o1); m2 = n2; }
    M2STAGE(0x111); M2STAGE(0x112); M2STAGE(0x114); M2STAGE(0x118); M2STAGE(0x142); M2STAGE(0x143);
    #undef M2STAGE
    w1 = __int_as_float(__builtin_amdgcn_readlane(__float_as_int(m1), 63));
    w2 = __int_as_float(__builtin_amdgcn_readlane(__float_as_int(m2), 63));
}

// ---- degree / dinv --------------------------------------------------------

__global__ void init_deg(float* deg1, float* deg2) {
    int v = blockIdx.x * blockDim.x + threadIdx.x;
    if (v < kN) { deg1[v] = 1.0f; deg2[v] = 1.0f; }
}

__global__ void scatter_deg(const int* ei1, const int* ei2, float* deg1, float* deg2) {
    int e = blockIdx.x * blockDim.x + threadIdx.x;
    if (e < kE) {
        atomicAdd(&deg1[ei1[kE + e]], 1.0f);
    } else if (e < 2 * kE) {
        atomicAdd(&deg2[ei2[kE + (e - kE)]], 1.0f);
    }
}

__global__ void deg_to_dinv(float* deg1, float* deg2) {
    int v = blockIdx.x * blockDim.x + threadIdx.x;
    if (v < kN) { deg1[v] = rsqrtf(deg1[v]); deg2[v] = rsqrtf(deg2[v]); }
}

// ---- GCN layer ------------------------------------------------------------

__global__ void gemm_act(const float* __restrict__ x, const float* __restrict__ w,
                         float* __restrict__ h, int FIN, int FOUT, int relu) {
    int idx = blockIdx.x * blockDim.x + threadIdx.x;
    if (idx >= kN * FOUT) return;
    int row = idx / FOUT;
    int oc  = idx - row * FOUT;
    float acc = 0.0f;
    for (int k = 0; k < FIN; ++k) {
        float xv = x[row * FIN + k];
        if (relu) xv = fmaxf(xv, 0.0f);
        acc += xv * w[k * FOUT + oc];
    }
    h[idx] = acc;
}

__global__ void agg_init(const float* __restrict__ h, const float* __restrict__ dinv,
                         const float* __restrict__ b, float* __restrict__ out, int F) {
    int idx = blockIdx.x * blockDim.x + threadIdx.x;
    if (idx >= kN * F) return;
    int v = idx / F;
    int f = idx - v * F;
    float dv = dinv[v];
    out[idx] = b[f] + dv * dv * h[idx];
}

__global__ void agg_edges(const int* __restrict__ ei, const float* __restrict__ h,
                          const float* __restrict__ dinv, float* __restrict__ out, int F) {
    int idx = blockIdx.x * blockDim.x + threadIdx.x;
    if (idx >= kE * F) return;
    int e = idx / F;
    int f = idx - e * F;
    int s = ei[e];
    int d = ei[kE + e];
    atomicAdd(&out[d * F + f], dinv[s] * dinv[d] * h[s * F + f]);
}

// ---- diag terms -----------------------------------------------------------

__global__ void node_dots(const float* __restrict__ f, const float* __restrict__ p,
                          float* __restrict__ out, int F) {
    int i = blockIdx.x * blockDim.x + threadIdx.x;
    if (i >= kN) return;
    float acc = 0.0f;
    for (int k = 0; k < F; ++k) acc += f[i * F + k] * p[k];
    out[i] = -acc;
}

// ---- reduced cost matrix + column minima ----------------------------------
// Entries <= 0 so uint bits are order-reversed: atomicMax == float min.

__global__ void build_cost_red(const float* __restrict__ f1, const float* __restrict__ f2,
                               const float* __restrict__ D, const float* __restrict__ I,
                               float* __restrict__ C, unsigned* __restrict__ vbits, int F) {
    int j = blockIdx.x * blockDim.x + threadIdx.x;
    int i = blockIdx.y;
    if (j >= kN) return;
    float acc = 0.0f;
    for (int k = 0; k < F; ++k) acc += f1[i * F + k] * f2[j * F + k];
    float val = (-acc) - D[i] - I[j];
    float c = fminf(0.0f, val);
    C[i * kN + j] = c;
    atomicMax(&vbits[j], __float_as_uint(c));
}

// ---- 384x384 exact JV LAP, one wave per matrix ----------------------------

__global__ __launch_bounds__(64) void lap384(const float* __restrict__ Call,
                                             const unsigned* __restrict__ vbits_all,
                                             const float* __restrict__ Dall,
                                             const float* __restrict__ Iall,
                                             float* __restrict__ loss_out) {
    const int m = blockIdx.x;
    const float* C = Call + (size_t)m * kN * kN;
    const unsigned* vb = vbits_all + m * kN;
    const int lane = threadIdx.x;

    __shared__ float u[kN], v[kN];
    __shared__ int xr[kN], yc[kN];     // row->col, col->row
    __shared__ int2 sp[kN];            // (bits of shortest dist, pred row)
    __shared__ int steps[kN];          // popped columns, in pop order
    __shared__ int2 yu[kN];            // (yc[j], bits of u[yc[j]])
    __shared__ int2 rbatch[kN];        // (row, u_bits) to relax this iteration
    __shared__ int flA[kN], flB[kN];   // ping-pong free-row lists
    __shared__ int fcl[kN];            // free-column list

    // --- init: v from column minima; clear assignment ---
    for (int j = lane; j < kN; j += 64) {
        v[j] = __uint_as_float(vb[j]);
        xr[j] = -1; yc[j] = -1;
        yu[j] = make_int2(-1, 0);
    }
    __syncthreads();

    float vreg[6];
    #pragma unroll
    for (int r = 0; r < 6; ++r) vreg[r] = v[lane + 64 * r];

    // --- fused u-init + greedy tight assignment (row-major, coalesced) ---
    // u[i]=w1 is BITWISE equal to C[i][cand]-v[cand] (fmin of those exprs).
    unsigned freemask = 0x3F;          // this lane's 6 columns free?
    int nf = 0;
    for (int i = 0; i < kN; ++i) {
        const float* Crow = C + (size_t)i * kN;
        float m1 = kInf; int j1loc = 0;
        #pragma unroll
        for (int r = 0; r < 6; ++r) {
            int j = lane + 64 * r;
            float hh = Crow[j] - vreg[r];
            if (hh < m1) { m1 = hh; j1loc = j; }
        }
        float w1 = wave_min_bcast(m1);
        int cloc = (m1 == w1 && ((freemask >> (j1loc >> 6)) & 1u)) ? j1loc : (1 << 30);
        unsigned long long mk = __ballot(cloc < (1 << 30));
        if (mk) {
            int cand = __builtin_amdgcn_readlane(cloc, __ffsll(mk) - 1);
            if (lane == (cand & 63)) freemask &= ~(1u << (cand >> 6));
            if (lane == 0) {
                xr[i] = cand; yc[cand] = i; u[i] = w1;
                yu[cand] = make_int2(i, __float_as_int(w1));
            }
        } else {
            if (lane == 0) { flA[nf] = i; u[i] = w1; }
            ++nf;
        }
    }

    // --- augmenting row reduction, 2 passes, tight-only, ping-pong lists ---
    int* src = flA; int* dst = flB;
    int f0 = nf;
    for (int pass = 0; pass < 2 && f0 > 0; ++pass) {
        int k = 0, f = 0, ops = 0;
        int i = -1;
        bool capped = false;
        for (;;) {
            if (i < 0) {
                if (k >= f0) break;
                i = src[k]; ++k;                     // uniform LDS broadcast
            }
            if (++ops > 4 * kN) {                    // churn guard
                if (lane == 0) dst[f] = i;
                ++f; capped = true; break;
            }
            const float* Crow = C + (size_t)i * kN;
            float m1 = kInf, m2 = kInf; int j1loc = 0;
            #pragma unroll
            for (int r = 0; r < 6; ++r) {
                int j = lane + 64 * r;
                float hh = Crow[j] - vreg[r];
                if (hh < m1) { m2 = m1; m1 = hh; j1loc = j; }
                else if (hh < m2) { m2 = hh; }
            }
            float w1, w2;
            wave_min2_bcast(m1, m2, w1, w2);
            unsigned long long mk = __ballot(m1 == w1);
            int j1 = __builtin_amdgcn_readlane(j1loc, __ffsll(mk) - 1);
            bool strict = (w1 < w2);
            int i0 = yc[j1];                         // uniform
            if (strict) {
                // lower v[j1]; recompute u bitwise-tight vs new v
                if (lane == (j1 & 63)) {
                    float nv = vreg[j1 >> 6] - (w2 - w1);
                    vreg[j1 >> 6] = nv; v[j1] = nv;
                }
                float uin = Crow[j1] - v[j1];        // uniform load + LDS read
                if (lane == 0) {
                    xr[i] = j1; yc[j1] = i; u[i] = uin;
                    yu[j1] = make_int2(i, __float_as_int(uin));
                }
                i = (i0 >= 0) ? i0 : -1;
            } else {
                // tie at w1==w2: (i,j1) tight bitwise with u[i]=w1
                if (lane == 0) {
                    xr[i] = j1; yc[j1] = i; u[i] = w1;
                    yu[j1] = make_int2(i, __float_as_int(w1));
                }
                if (i0 >= 0) { if (lane == 0) dst[f] = i0; ++f; }
                i = -1;
            }
        }
        if (capped) {                                // append unprocessed tail
            for (int t = k + lane; t < f0; t += 64) dst[f + (t - k)] = src[t];
            f += f0 - k;
        }
        int* tmp = src; src = dst; dst = tmp;
        f0 = f;
    }
    __syncthreads();

    // --- free-column dual reduction: v[j] = min_i (C[i][j] - u[i]) ---------
    {
        int fc = 0;
        for (int base = 0; base < kN; base += 64) {
            int j = base + lane;
            bool isfree = (yc[j] < 0);
            unsigned long long mk = __ballot(isfree);
            int pos = fc + __popcll(mk & ((1ull << lane) - 1ull));
            if (isfree) fcl[pos] = j;
            fc += (int)__popcll(mk);
        }
        __syncthreads();
        for (int t = lane; t < fc; t += 64) {
            int j = fcl[t];
            float mn = kInf;
            #pragma unroll 4
            for (int i = 0; i < kN; ++i)
                mn = fminf(mn, C[(size_t)i * kN + j] - u[i]);
            v[j] = mn;
        }
        __syncthreads();
    }

    // --- shortest augmenting path w/ batched exact tie-popping -------------
    const int nfree = f0;
    for (int fi = 0; fi < nfree; ++fi) {
        const int cur = src[fi];
        float sreg[6];
        unsigned scmask = 0;
        #pragma unroll
        for (int r = 0; r < 6; ++r) { sreg[r] = kInf; vreg[r] = v[lane + 64 * r]; }
        float min_val = 0.0f;
        int sink = -1;
        int scount = 0;
        int nbatch = 1;
        int iters = 0;
        if (lane == 0) rbatch[0] = make_int2(cur, __float_as_int(u[cur]));
        __syncthreads();

        while (true) {
            // relax all rows in rbatch, chunks of 8 (padded with last entry).
            // d = min_val + ((c - v) - u): tight edges give EXACTLY min_val.
            for (int t0 = 0; t0 < nbatch; t0 += 8) {
                int rw[8]; const float* R[8]; float uu[8];
                #pragma unroll
                for (int q = 0; q < 8; ++q) {
                    int idx = t0 + q; if (idx >= nbatch) idx = nbatch - 1;
                    int2 e = rbatch[idx];
                    rw[q] = e.x;
                    uu[q] = __int_as_float(e.y);
                    R[q]  = C + (size_t)e.x * kN;
                }
                float cc[8][6];
                #pragma unroll
                for (int q = 0; q < 8; ++q) {
                    #pragma unroll
                    for (int r = 0; r < 6; ++r) cc[q][r] = R[q][lane + 64 * r];
                }
                #pragma unroll
                for (int r = 0; r < 6; ++r) {
                    float db = sreg[r]; int pred = -1;
                    #pragma unroll
                    for (int q = 0; q < 8; ++q) {
                        float d = min_val + ((cc[q][r] - vreg[r]) - uu[q]);
                        if (d < db) { db = d; pred = rw[q]; }
                    }
                    bool notsc = ((scmask >> r) & 1u) == 0u;
                    if (notsc && pred >= 0) {
                        sreg[r] = db;
                        sp[lane + 64 * r] = make_int2(__float_as_int(db), pred);
                    }
                }
            }

            // global min over remaining (non-popped) columns
            float best = fminf(fminf(fminf(sreg[0], sreg[1]), fminf(sreg[2], sreg[3])),
                               fminf(sreg[4], sreg[5]));
            min_val = wave_min_bcast(best);

            // pop ALL columns at min_val (bitwise ties pop together)
            nbatch = 0;
            #pragma unroll
            for (int r = 0; r < 6; ++r) {
                bool notsc = ((scmask >> r) & 1u) == 0u;
                bool elig = notsc && (sreg[r] == min_val);
                unsigned long long mk = __ballot(elig);
                if (mk == 0) continue;
                int j = lane + 64 * r;
                int2 p = make_int2(0, 0);
                if (elig) { p = yu[j]; sreg[r] = kInf; scmask |= 1u << r; }
                int pos = (int)__popcll(mk & ((1ull << lane) - 1ull));
                if (elig) {
                    steps[scount + pos] = j;
                    rbatch[nbatch + pos] = p;
                }
                int cnt = (int)__popcll(mk);
                unsigned long long fmk = __ballot(elig && p.x < 0);
                if (fmk != 0 && sink < 0) sink = (__ffsll(fmk) - 1) + 64 * r;
                scount += cnt; nbatch += cnt;
            }
            if (sink >= 0) break;
            if (++iters > kN + 1) break;             // safety; never in practice
            __syncthreads();   // order LDS rbatch writes before next relax
        }

        __syncthreads();
        if (sink >= 0) {
            // v updates per popped column; u handled by tight recompute below
            for (int t = lane; t < scount; t += 64) {
                int jc = steps[t];
                v[jc] -= min_val - __int_as_float(sp[jc].x);
            }
            __syncthreads();
            if (lane == 0) {                         // augment along path
                int j = sink;
                for (;;) {
                    int ii = sp[j].y;
                    yc[j] = ii;
                    int nxt = xr[ii];
                    xr[ii] = j;
                    j = nxt;
                    if (ii == cur) break;
                }
            }
            __syncthreads();
            // recompute u bitwise-tight for every popped column's owner
            for (int t = lane; t < scount; t += 64) {
                int jc = steps[t];
                int yy = yc[jc];
                if (yy >= 0) {
                    float un = C[(size_t)yy * kN + jc] - v[jc];
                    u[yy] = un;
                    yu[jc] = make_int2(yy, __float_as_int(un));
                }
            }
            __syncthreads();
        }
    }

    // --- loss = Sum D + Sum I + Sum_i C[i, x[i]] ---
    float s = 0.0f;
    for (int t = lane; t < kN; t += 64) {
        s += C[(size_t)t * kN + xr[t]];
        s += Dall[m * kN + t] + Iall[m * kN + t];
    }
    #pragma unroll
    for (int off = 32; off > 0; off >>= 1) s += __shfl_down(s, off);
    if (lane == 0) loss_out[m] = s;
}

// ---- finalize -------------------------------------------------------------

__global__ void finalize(const float* __restrict__ loss_sums,
                         const float* __restrict__ score_w,
                         const float* __restrict__ score_b,
                         const float* __restrict__ avg_v,
                         float* __restrict__ out) {
    float mc[3];
    for (int m = 0; m < 3; ++m) mc[m] = 2.0f * (loss_sums[m] / (float)kNN) / (float)kNN;
    float logits = score_b[0];
    for (int m = 0; m < 3; ++m) logits += score_w[m] * mc[m];
    float score = 1.0f / (1.0f + expf(-logits));
    out[0] = score;
    out[1] = -logf(score) * avg_v[0];
    out[2] = mc[0];
    out[3] = mc[1];
    out[4] = mc[2];
}

// ---------------------------------------------------------------------------

extern "C" void kernel_launch(void* const* d_in, const int* in_sizes, int n_in,
                              void* d_out, int out_size, void* d_ws, size_t ws_size,
                              hipStream_t stream) {
    const int*   ei1 = (const int*)d_in[0];
    const int*   ei2 = (const int*)d_in[1];
    const float* x1  = (const float*)d_in[2];
    const float* x2  = (const float*)d_in[3];
    const float* avg = (const float*)d_in[6];

    const float *w[3], *b[3], *dl[3], *insp[3], *score_w, *score_b;
    if (in_sizes[11] == 8192) {  // dict order
        w[0]=(const float*)d_in[7];  b[0]=(const float*)d_in[8];
        dl[0]=(const float*)d_in[9]; insp[0]=(const float*)d_in[10];
        w[1]=(const float*)d_in[11]; b[1]=(const float*)d_in[12];
        dl[1]=(const float*)d_in[13]; insp[1]=(const float*)d_in[14];
        w[2]=(const float*)d_in[15]; b[2]=(const float*)d_in[16];
        dl[2]=(const float*)d_in[17]; insp[2]=(const float*)d_in[18];
        score_w=(const float*)d_in[19]; score_b=(const float*)d_in[20];
    } else {                     // signature order
        w[0]=(const float*)d_in[7];  b[0]=(const float*)d_in[8];
        w[1]=(const float*)d_in[9];  b[1]=(const float*)d_in[10];
        w[2]=(const float*)d_in[11]; b[2]=(const float*)d_in[12];
        dl[0]=(const float*)d_in[13]; dl[1]=(const float*)d_in[14]; dl[2]=(const float*)d_in[15];
        insp[0]=(const float*)d_in[16]; insp[1]=(const float*)d_in[17]; insp[2]=(const float*)d_in[18];
        score_w=(const float*)d_in[19]; score_b=(const float*)d_in[20];
    }

    // Workspace layout (float offsets)
    float* ws = (float*)d_ws;
    float* f1[3]  = { ws + 0,      ws + 49152,  ws + 73728  };  // 384x{128,64,32}
    float* f2[3]  = { ws + 86016,  ws + 135168, ws + 159744 };
    float* h      = ws + 172032;                                // 384x128 temp
    float* dinv1  = ws + 221184;
    float* dinv2  = ws + 221568;
    float* Dm     = ws + 221952;                                // 3 x 384
    float* Im     = ws + 223104;                                // 3 x 384
    unsigned* vbits = (unsigned*)(ws + 224256);                 // 3 x 384
    float* C      = ws + 225408;                                // 3 x 384 x 384
    float* loss   = ws + 667776;                                // 3

    init_deg<<<6, 64, 0, stream>>>(dinv1, dinv2);
    scatter_deg<<<24, 256, 0, stream>>>(ei1, ei2, dinv1, dinv2);
    deg_to_dinv<<<6, 64, 0, stream>>>(dinv1, dinv2);

    const int Fs[3] = {128, 64, 32};
    for (int g = 0; g < 2; ++g) {
        const float* xin  = g ? x2  : x1;
        const int*   ei   = g ? ei2 : ei1;
        float*       dinv = g ? dinv2 : dinv1;
        float* const* f   = g ? f2 : f1;
        int fin = 32, relu = 0;
        for (int li = 0; li < 3; ++li) {
            int OF = Fs[li];
            int nthr = kN * OF;
            gemm_act<<<(nthr + 255) / 256, 256, 0, stream>>>(xin, w[li], h, fin, OF, relu);
            agg_init<<<(nthr + 255) / 256, 256, 0, stream>>>(h, dinv, b[li], f[li], OF);
            agg_edges<<<(kE * OF + 255) / 256, 256, 0, stream>>>(ei, h, dinv, f[li], OF);
            xin = f[li]; fin = OF; relu = 1;
        }
    }

    hipMemsetAsync(vbits, 0, 3 * kN * sizeof(unsigned), stream);  // 0 == bits of +0.0f

    for (int m = 0; m < 3; ++m) {
        node_dots<<<3, 128, 0, stream>>>(f1[m], dl[m],   Dm + m * kN, Fs[m]);
        node_dots<<<3, 128, 0, stream>>>(f2[m], insp[m], Im + m * kN, Fs[m]);
        build_cost_red<<<dim3(3, kN), 128, 0, stream>>>(f1[m], f2[m], Dm + m * kN,
                                                        Im + m * kN,
                                                        C + (size_t)m * kN * kN,
                                                        vbits + m * kN, Fs[m]);
    }

    lap384<<<3, 64, 0, stream>>>(C, vbits, Dm, Im, loss);
    finalize<<<1, 1, 0, stream>>>(loss, score_w, score_b, avg, (float*)d_out);
}

// Round 10
// 42528.537 us; speedup vs baseline: 1.0292x; 1.0292x over previous
//
#include <hip/hip_runtime.h>
#include <math.h>

// ---------------------------------------------------------------------------
// GOTSim: GCN features -> reduced 384x384 LAP (exact JV: col-reduction +
// fused greedy/u-init + augmenting row reduction + free-column dual
// reduction + MULTI-SOURCE shortest augmenting path: every free row is a
// zero-distance Dijkstra source; first free column popped ends the phase;
// dual update raises u of ALL remaining free rows by delta each phase).
// Invariant: {rows with xr==-1} == src[0..nf_sh) (ARR clears xr on displace).
// LAP_768(block) = Sum(D)+Sum(I) + LAP_384(min(0, M_ij - D_i - I_j)).
// ---------------------------------------------------------------------------

namespace {
constexpr int kN   = 384;   // nodes per graph == reduced LAP dimension
constexpr int kNN  = 768;   // original LAP dimension (for normalization)
constexpr int kE   = 3072;  // edges per graph
constexpr float kInf = 1e30f;
}

// ---- wave64 reductions via DPP (row_shr 1,2,4,8 + row_bcast 15,31) --------
__device__ __forceinline__ float wave_min_bcast(float xv) {
    float v = xv;
    #define MSTAGE(ctrl) { int t = __builtin_amdgcn_update_dpp(__float_as_int(v), __float_as_int(v), ctrl, 0xF, 0xF, false); v = fminf(v, __int_as_float(t)); }
    MSTAGE(0x111); MSTAGE(0x112); MSTAGE(0x114); MSTAGE(0x118); MSTAGE(0x142); MSTAGE(0x143);
    #undef MSTAGE
    return __int_as_float(__builtin_amdgcn_readlane(__float_as_int(v), 63));
}

// (min, second-min): disabled lanes contribute identity (+inf) via old=INF.
__device__ __forceinline__ void wave_min2_bcast(float m1, float m2, float& w1, float& w2) {
    const int INFB = __float_as_int(kInf);
    #define M2STAGE(ctrl) { \
        int t1 = __builtin_amdgcn_update_dpp(INFB, __float_as_int(m1), ctrl, 0xF, 0xF, false); \
        int t2 = __builtin_amdgcn_update_dpp(INFB, __float_as_int(m2), ctrl, 0xF, 0xF, false); \
        float o1 = __int_as_float(t1); float o2 = __int_as_float(t2); \
        float n2 = fminf(fmaxf(m1, o1), fminf(m2, o2)); \
        m1 = fminf(m1, o1); m2 = n2; }
    M2STAGE(0x111); M2STAGE(0x112); M2STAGE(0x114); M2STAGE(0x118); M2STAGE(0x142); M2STAGE(0x143);
    #undef M2STAGE
    w1 = __int_as_float(__builtin_amdgcn_readlane(__float_as_int(m1), 63));
    w2 = __int_as_float(__builtin_amdgcn_readlane(__float_as_int(m2), 63));
}

// ---- degree / dinv --------------------------------------------------------

__global__ void init_deg(float* deg1, float* deg2) {
    int v = blockIdx.x * blockDim.x + threadIdx.x;
    if (v < kN) { deg1[v] = 1.0f; deg2[v] = 1.0f; }
}

__global__ void scatter_deg(const int* ei1, const int* ei2, float* deg1, float* deg2) {
    int e = blockIdx.x * blockDim.x + threadIdx.x;
    if (e < kE) {
        atomicAdd(&deg1[ei1[kE + e]], 1.0f);
    } else if (e < 2 * kE) {
        atomicAdd(&deg2[ei2[kE + (e - kE)]], 1.0f);
    }
}

__global__ void deg_to_dinv(float* deg1, float* deg2) {
    int v = blockIdx.x * blockDim.x + threadIdx.x;
    if (v < kN) { deg1[v] = rsqrtf(deg1[v]); deg2[v] = rsqrtf(deg2[v]); }
}

// ---- GCN layer ------------------------------------------------------------

__global__ void gemm_act(const float* __restrict__ x, const float* __restrict__ w,
                         float* __restrict__ h, int FIN, int FOUT, int relu) {
    int idx = blockIdx.x * blockDim.x + threadIdx.x;
    if (idx >= kN * FOUT) return;
    int row = idx / FOUT;
    int oc  = idx - row * FOUT;
    float acc = 0.0f;
    for (int k = 0; k < FIN; ++k) {
        float xv = x[row * FIN + k];
        if (relu) xv = fmaxf(xv, 0.0f);
        acc += xv * w[k * FOUT + oc];
    }
    h[idx] = acc;
}

__global__ void agg_init(const float* __restrict__ h, const float* __restrict__ dinv,
                         const float* __restrict__ b, float* __restrict__ out, int F) {
    int idx = blockIdx.x * blockDim.x + threadIdx.x;
    if (idx >= kN * F) return;
    int v = idx / F;
    int f = idx - v * F;
    float dv = dinv[v];
    out[idx] = b[f] + dv * dv * h[idx];
}

__global__ void agg_edges(const int* __restrict__ ei, const float* __restrict__ h,
                          const float* __restrict__ dinv, float* __restrict__ out, int F) {
    int idx = blockIdx.x * blockDim.x + threadIdx.x;
    if (idx >= kE * F) return;
    int e = idx / F;
    int f = idx - e * F;
    int s = ei[e];
    int d = ei[kE + e];
    atomicAdd(&out[d * F + f], dinv[s] * dinv[d] * h[s * F + f]);
}

// ---- diag terms -----------------------------------------------------------

__global__ void node_dots(const float* __restrict__ f, const float* __restrict__ p,
                          float* __restrict__ out, int F) {
    int i = blockIdx.x * blockDim.x + threadIdx.x;
    if (i >= kN) return;
    float acc = 0.0f;
    for (int k = 0; k < F; ++k) acc += f[i * F + k] * p[k];
    out[i] = -acc;
}

// ---- reduced cost matrix + column minima ----------------------------------
// Entries <= 0 so uint bits are order-reversed: atomicMax == float min.

__global__ void build_cost_red(const float* __restrict__ f1, const float* __restrict__ f2,
                               const float* __restrict__ D, const float* __restrict__ I,
                               float* __restrict__ C, unsigned* __restrict__ vbits, int F) {
    int j = blockIdx.x * blockDim.x + threadIdx.x;
    int i = blockIdx.y;
    if (j >= kN) return;
    float acc = 0.0f;
    for (int k = 0; k < F; ++k) acc += f1[i * F + k] * f2[j * F + k];
    float val = (-acc) - D[i] - I[j];
    float c = fminf(0.0f, val);
    C[i * kN + j] = c;
    atomicMax(&vbits[j], __float_as_uint(c));
}

// ---- 384x384 exact JV LAP, one wave per matrix ----------------------------

__global__ __launch_bounds__(64) void lap384(const float* __restrict__ Call,
                                             const unsigned* __restrict__ vbits_all,
                                             const float* __restrict__ Dall,
                                             const float* __restrict__ Iall,
                                             float* __restrict__ loss_out) {
    const int m = blockIdx.x;
    const float* C = Call + (size_t)m * kN * kN;
    const unsigned* vb = vbits_all + m * kN;
    const int lane = threadIdx.x;

    __shared__ float u[kN], v[kN];
    __shared__ int xr[kN], yc[kN];     // row->col, col->row
    __shared__ int2 sp[kN];            // (bits of shortest dist, pred row)
    __shared__ int steps[kN];          // popped columns, in pop order
    __shared__ int2 yu[kN];            // (yc[j], bits of u[yc[j]])
    __shared__ int2 rbatch[kN];        // (row, u_bits) to relax this iteration
    __shared__ int flA[kN], flB[kN];   // ping-pong free-row lists
    __shared__ int fcl[kN];            // free-column list
    __shared__ int nf_sh;

    // --- init: v from column minima; clear assignment ---
    for (int j = lane; j < kN; j += 64) {
        v[j] = __uint_as_float(vb[j]);
        xr[j] = -1; yc[j] = -1;
        yu[j] = make_int2(-1, 0);
    }
    __syncthreads();

    float vreg[6];
    #pragma unroll
    for (int r = 0; r < 6; ++r) vreg[r] = v[lane + 64 * r];

    // --- fused u-init + greedy tight assignment (row-major, coalesced) ---
    // u[i]=w1 is BITWISE equal to C[i][cand]-v[cand] (fmin of those exprs).
    unsigned freemask = 0x3F;          // this lane's 6 columns free?
    int nf = 0;
    for (int i = 0; i < kN; ++i) {
        const float* Crow = C + (size_t)i * kN;
        float m1 = kInf; int j1loc = 0;
        #pragma unroll
        for (int r = 0; r < 6; ++r) {
            int j = lane + 64 * r;
            float hh = Crow[j] - vreg[r];
            if (hh < m1) { m1 = hh; j1loc = j; }
        }
        float w1 = wave_min_bcast(m1);
        int cloc = (m1 == w1 && ((freemask >> (j1loc >> 6)) & 1u)) ? j1loc : (1 << 30);
        unsigned long long mk = __ballot(cloc < (1 << 30));
        if (mk) {
            int cand = __builtin_amdgcn_readlane(cloc, __ffsll(mk) - 1);
            if (lane == (cand & 63)) freemask &= ~(1u << (cand >> 6));
            if (lane == 0) {
                xr[i] = cand; yc[cand] = i; u[i] = w1;
                yu[cand] = make_int2(i, __float_as_int(w1));
            }
        } else {
            if (lane == 0) { flA[nf] = i; u[i] = w1; }
            ++nf;
        }
    }

    // --- augmenting row reduction, 2 passes, tight-only, ping-pong lists ---
    // Displaced rows get xr=-1 (multi-source SAP relies on the invariant).
    int* src = flA; int* dst = flB;
    int f0 = nf;
    for (int pass = 0; pass < 2 && f0 > 0; ++pass) {
        int k = 0, f = 0, ops = 0;
        int i = -1;
        bool capped = false;
        for (;;) {
            if (i < 0) {
                if (k >= f0) break;
                i = src[k]; ++k;                     // uniform LDS broadcast
            }
            if (++ops > 4 * kN) {                    // churn guard
                if (lane == 0) { dst[f] = i; xr[i] = -1; }
                ++f; capped = true; break;
            }
            const float* Crow = C + (size_t)i * kN;
            float m1 = kInf, m2 = kInf; int j1loc = 0;
            #pragma unroll
            for (int r = 0; r < 6; ++r) {
                int j = lane + 64 * r;
                float hh = Crow[j] - vreg[r];
                if (hh < m1) { m2 = m1; m1 = hh; j1loc = j; }
                else if (hh < m2) { m2 = hh; }
            }
            float w1, w2;
            wave_min2_bcast(m1, m2, w1, w2);
            unsigned long long mk = __ballot(m1 == w1);
            int j1 = __builtin_amdgcn_readlane(j1loc, __ffsll(mk) - 1);
            bool strict = (w1 < w2);
            int i0 = yc[j1];                         // uniform
            if (strict) {
                // lower v[j1]; recompute u bitwise-tight vs new v
                if (lane == (j1 & 63)) {
                    float nv = vreg[j1 >> 6] - (w2 - w1);
                    vreg[j1 >> 6] = nv; v[j1] = nv;
                }
                float uin = Crow[j1] - v[j1];        // uniform load + LDS read
                if (lane == 0) {
                    xr[i] = j1; yc[j1] = i; u[i] = uin;
                    yu[j1] = make_int2(i, __float_as_int(uin));
                    if (i0 >= 0) xr[i0] = -1;        // displaced: now free
                }
                i = (i0 >= 0) ? i0 : -1;             // reprocess immediately
            } else {
                // tie at w1==w2: (i,j1) tight bitwise with u[i]=w1
                if (lane == 0) {
                    xr[i] = j1; yc[j1] = i; u[i] = w1;
                    yu[j1] = make_int2(i, __float_as_int(w1));
                    if (i0 >= 0) { dst[f] = i0; xr[i0] = -1; }
                }
                if (i0 >= 0) ++f;
                i = -1;
            }
        }
        if (capped) {                                // append unprocessed tail
            for (int t = k + lane; t < f0; t += 64) dst[f + (t - k)] = src[t];
            f += f0 - k;
        }
        int* tmp = src; src = dst; dst = tmp;
        f0 = f;
    }
    __syncthreads();

    // --- free-column dual reduction: v[j] = min_i (C[i][j] - u[i]) ---------
    {
        int fc = 0;
        for (int base = 0; base < kN; base += 64) {
            int j = base + lane;
            bool isfree = (yc[j] < 0);
            unsigned long long mk = __ballot(isfree);
            int pos = fc + __popcll(mk & ((1ull << lane) - 1ull));
            if (isfree) fcl[pos] = j;
            fc += (int)__popcll(mk);
        }
        __syncthreads();
        for (int t = lane; t < fc; t += 64) {
            int j = fcl[t];
            float mn = kInf;
            #pragma unroll 4
            for (int i = 0; i < kN; ++i)
                mn = fminf(mn, C[(size_t)i * kN + j] - u[i]);
            v[j] = mn;
        }
        __syncthreads();
    }

    // --- MULTI-SOURCE shortest augmenting path phases ----------------------
    // All free rows are Dijkstra sources (d=0). First free column popped
    // terminates the phase; standard SSP dual update gives u[r] += delta
    // for every remaining free row -> later floods shrink fast.
    if (lane == 0) nf_sh = f0;
    __syncthreads();

    while (true) {
        const int nfr = nf_sh;
        if (nfr <= 0) break;

        float sreg[6];
        unsigned scmask = 0;
        #pragma unroll
        for (int r = 0; r < 6; ++r) { sreg[r] = kInf; vreg[r] = v[lane + 64 * r]; }
        float min_val = 0.0f;
        int sink = -1, scount = 0, iters = 0;
        int nbatch = nfr;
        for (int t = lane; t < nfr; t += 64) {
            int rr = src[t];
            rbatch[t] = make_int2(rr, __float_as_int(u[rr]));
        }
        __syncthreads();

        while (true) {
            // relax rows in rbatch. d = min_val + ((c - v) - u): bitwise-tight
            // edges reproduce min_val exactly (tie-pop bonus when it occurs).
            if (nbatch == 1) {                       // fast path: no dup loads
                int2 e = rbatch[0];
                float uu = __int_as_float(e.y);
                const float* R = C + (size_t)e.x * kN;
                float cc[6];
                #pragma unroll
                for (int r = 0; r < 6; ++r) cc[r] = R[lane + 64 * r];
                #pragma unroll
                for (int r = 0; r < 6; ++r) {
                    float d = min_val + ((cc[r] - vreg[r]) - uu);
                    bool notsc = ((scmask >> r) & 1u) == 0u;
                    if (notsc && d < sreg[r]) {
                        sreg[r] = d;
                        sp[lane + 64 * r] = make_int2(__float_as_int(d), e.x);
                    }
                }
            } else {
                for (int t0 = 0; t0 < nbatch; t0 += 4) {
                    int rw[4]; const float* R[4]; float uu[4];
                    #pragma unroll
                    for (int q = 0; q < 4; ++q) {
                        int idx = t0 + q; if (idx >= nbatch) idx = nbatch - 1;
                        int2 e = rbatch[idx];
                        rw[q] = e.x;
                        uu[q] = __int_as_float(e.y);
                        R[q]  = C + (size_t)e.x * kN;
                    }
                    float cc[4][6];
                    #pragma unroll
                    for (int q = 0; q < 4; ++q) {
                        #pragma unroll
                        for (int r = 0; r < 6; ++r) cc[q][r] = R[q][lane + 64 * r];
                    }
                    #pragma unroll
                    for (int r = 0; r < 6; ++r) {
                        float db = sreg[r]; int pred = -1;
                        #pragma unroll
                        for (int q = 0; q < 4; ++q) {
                            float d = min_val + ((cc[q][r] - vreg[r]) - uu[q]);
                            if (d < db) { db = d; pred = rw[q]; }
                        }
                        bool notsc = ((scmask >> r) & 1u) == 0u;
                        if (notsc && pred >= 0) {
                            sreg[r] = db;
                            sp[lane + 64 * r] = make_int2(__float_as_int(db), pred);
                        }
                    }
                }
            }

            // global min over remaining (non-popped) columns
            float best = fminf(fminf(fminf(sreg[0], sreg[1]), fminf(sreg[2], sreg[3])),
                               fminf(sreg[4], sreg[5]));
            min_val = wave_min_bcast(best);

            // pop ALL columns at min_val
            nbatch = 0;
            #pragma unroll
            for (int r = 0; r < 6; ++r) {
                bool notsc = ((scmask >> r) & 1u) == 0u;
                bool elig = notsc && (sreg[r] == min_val);
                unsigned long long mk = __ballot(elig);
                if (mk == 0) continue;
                int j = lane + 64 * r;
                int2 p = make_int2(0, 0);
                if (elig) { p = yu[j]; sreg[r] = kInf; scmask |= 1u << r; }
                int pos = (int)__popcll(mk & ((1ull << lane) - 1ull));
                if (elig) {
                    steps[scount + pos] = j;
                    rbatch[nbatch + pos] = p;
                }
                int cnt = (int)__popcll(mk);
                unsigned long long fmk = __ballot(elig && p.x < 0);
                if (fmk != 0 && sink < 0) sink = (__ffsll(fmk) - 1) + 64 * r;
                scount += cnt; nbatch += cnt;
            }
            if (sink >= 0) break;
            if (++iters > kN + 2) break;             // safety; never in practice
            __syncthreads();   // order LDS rbatch writes before next relax
        }

        __syncthreads();
        if (sink < 0) break;                         // safety: bail out

        // v updates per popped column (sink popped at d==delta: no-op there)
        for (int t = lane; t < scount; t += 64) {
            int jc = steps[t];
            v[jc] -= min_val - __int_as_float(sp[jc].x);
        }
        __syncthreads();
        if (lane == 0) {                             // augment; ends at a free row
            int j = sink;
            int matched = -1;
            int guard = 0;
            for (;;) {
                int ii = sp[j].y;
                yc[j] = ii;
                int nxt = xr[ii];
                xr[ii] = j;
                j = nxt;
                if (nxt < 0) { matched = ii; break; }
                if (++guard > kN) { matched = ii; break; }  // safety
            }
            int n2 = nf_sh;                          // remove matched row;
            for (int t = 0; t < n2; ++t) {           // ALWAYS shrink (progress)
                if (src[t] == matched) { src[t] = src[n2 - 1]; break; }
            }
            nf_sh = n2 - 1;
        }
        __syncthreads();
        // recompute u bitwise-tight for every popped column's (new) owner
        for (int t = lane; t < scount; t += 64) {
            int jc = steps[t];
            int yy = yc[jc];
            if (yy >= 0) {
                float un = C[(size_t)yy * kN + jc] - v[jc];
                u[yy] = un;
                yu[jc] = make_int2(yy, __float_as_int(un));
            }
        }
        __syncthreads();
        // remaining free rows: u += delta (standard multi-source dual update)
        for (int t = lane; t < nf_sh; t += 64) u[src[t]] += min_val;
        __syncthreads();
    }

    // --- loss = Sum D + Sum I + Sum_i C[i, x[i]] ---
    float s = 0.0f;
    for (int t = lane; t < kN; t += 64) {
        int c_ = xr[t];
        if (c_ >= 0) s += C[(size_t)t * kN + c_];
        s += Dall[m * kN + t] + Iall[m * kN + t];
    }
    #pragma unroll
    for (int off = 32; off > 0; off >>= 1) s += __shfl_down(s, off);
    if (lane == 0) loss_out[m] = s;
}

// ---- finalize -------------------------------------------------------------

__global__ void finalize(const float* __restrict__ loss_sums,
                         const float* __restrict__ score_w,
                         const float* __restrict__ score_b,
                         const float* __restrict__ avg_v,
                         float* __restrict__ out) {
    float mc[3];
    for (int m = 0; m < 3; ++m) mc[m] = 2.0f * (loss_sums[m] / (float)kNN) / (float)kNN;
    float logits = score_b[0];
    for (int m = 0; m < 3; ++m) logits += score_w[m] * mc[m];
    float score = 1.0f / (1.0f + expf(-logits));
    out[0] = score;
    out[1] = -logf(score) * avg_v[0];
    out[2] = mc[0];
    out[3] = mc[1];
    out[4] = mc[2];
}

// ---------------------------------------------------------------------------

extern "C" void kernel_launch(void* const* d_in, const int* in_sizes, int n_in,
                              void* d_out, int out_size, void* d_ws, size_t ws_size,
                              hipStream_t stream) {
    const int*   ei1 = (const int*)d_in[0];
    const int*   ei2 = (const int*)d_in[1];
    const float* x1  = (const float*)d_in[2];
    const float* x2  = (const float*)d_in[3];
    const float* avg = (const float*)d_in[6];

    const float *w[3], *b[3], *dl[3], *insp[3], *score_w, *score_b;
    if (in_sizes[11] == 8192) {  // dict order
        w[0]=(const float*)d_in[7];  b[0]=(const float*)d_in[8];
        dl[0]=(const float*)d_in[9]; insp[0]=(const float*)d_in[10];
        w[1]=(const float*)d_in[11]; b[1]=(const float*)d_in[12];
        dl[1]=(const float*)d_in[13]; insp[1]=(const float*)d_in[14];
        w[2]=(const float*)d_in[15]; b[2]=(const float*)d_in[16];
        dl[2]=(const float*)d_in[17]; insp[2]=(const float*)d_in[18];
        score_w=(const float*)d_in[19]; score_b=(const float*)d_in[20];
    } else {                     // signature order
        w[0]=(const float*)d_in[7];  b[0]=(const float*)d_in[8];
        w[1]=(const float*)d_in[9];  b[1]=(const float*)d_in[10];
        w[2]=(const float*)d_in[11]; b[2]=(const float*)d_in[12];
        dl[0]=(const float*)d_in[13]; dl[1]=(const float*)d_in[14]; dl[2]=(const float*)d_in[15];
        insp[0]=(const float*)d_in[16]; insp[1]=(const float*)d_in[17]; insp[2]=(const float*)d_in[18];
        score_w=(const float*)d_in[19]; score_b=(const float*)d_in[20];
    }

    // Workspace layout (float offsets)
    float* ws = (float*)d_ws;
    float* f1[3]  = { ws + 0,      ws + 49152,  ws + 73728  };  // 384x{128,64,32}
    float* f2[3]  = { ws + 86016,  ws + 135168, ws + 159744 };
    float* h      = ws + 172032;                                // 384x128 temp
    float* dinv1  = ws + 221184;
    float* dinv2  = ws + 221568;
    float* Dm     = ws + 221952;                                // 3 x 384
    float* Im     = ws + 223104;                                // 3 x 384
    unsigned* vbits = (unsigned*)(ws + 224256);                 // 3 x 384
    float* C      = ws + 225408;                                // 3 x 384 x 384
    float* loss   = ws + 667776;                                // 3

    init_deg<<<6, 64, 0, stream>>>(dinv1, dinv2);
    scatter_deg<<<24, 256, 0, stream>>>(ei1, ei2, dinv1, dinv2);
    deg_to_dinv<<<6, 64, 0, stream>>>(dinv1, dinv2);

    const int Fs[3] = {128, 64, 32};
    for (int g = 0; g < 2; ++g) {
        const float* xin  = g ? x2  : x1;
        const int*   ei   = g ? ei2 : ei1;
        float*       dinv = g ? dinv2 : dinv1;
        float* const* f   = g ? f2 : f1;
        int fin = 32, relu = 0;
        for (int li = 0; li < 3; ++li) {
            int OF = Fs[li];
            int nthr = kN * OF;
            gemm_act<<<(nthr + 255) / 256, 256, 0, stream>>>(xin, w[li], h, fin, OF, relu);
            agg_init<<<(nthr + 255) / 256, 256, 0, stream>>>(h, dinv, b[li], f[li], OF);
            agg_edges<<<(kE * OF + 255) / 256, 256, 0, stream>>>(ei, h, dinv, f[li], OF);
            xin = f[li]; fin = OF; relu = 1;
        }
    }

    hipMemsetAsync(vbits, 0, 3 * kN * sizeof(unsigned), stream);  // 0 == bits of +0.0f

    for (int m = 0; m < 3; ++m) {
        node_dots<<<3, 128, 0, stream>>>(f1[m], dl[m],   Dm + m * kN, Fs[m]);
        node_dots<<<3, 128, 0, stream>>>(f2[m], insp[m], Im + m * kN, Fs[m]);
        build_cost_red<<<dim3(3, kN), 128, 0, stream>>>(f1[m], f2[m], Dm + m * kN,
                                                        Im + m * kN,
                                                        C + (size_t)m * kN * kN,
                                                        vbits + m * kN, Fs[m]);
    }

    lap384<<<3, 64, 0, stream>>>(C, vbits, Dm, Im, loss);
    finalize<<<1, 1, 0, stream>>>(loss, score_w, score_b, avg, (float*)d_out);
}